// Round 2
// baseline (1496.442 us; speedup 1.0000x reference)
//
#include <hip/hip_runtime.h>

typedef unsigned short u16;
typedef unsigned int   u32;
typedef unsigned long long u64;
typedef __attribute__((ext_vector_type(8))) short bf16x8;
typedef __attribute__((ext_vector_type(4))) float f32x4;

#define GK 768            // K dim of all GEMMs
#define NSTEP 196
#define HSTEP 49152       // 64*768 elements per step slab
#define PWG 24            // workgroups per batch-group (8 groups x 24 = 192 active)
#define NBLK 256          // launched workgroups (claim protocol)
#define FLAG0 32          // fast step-flags base (plain stores, XCD-local L2)
#define MIR0 512          // agent-scope mirror flags base (liveness rescue)

__device__ __forceinline__ u16 f2bf(float f) {
    u32 u = __float_as_uint(f);
    u = (u + 0x7fffu + ((u >> 16) & 1u)) >> 16;
    return (u16)u;
}
__device__ __forceinline__ float bf2f(u16 h) { return __uint_as_float(((u32)h) << 16); }

// ---------------------------------------------------------------------------
// fp32 -> bf16 convert for x, Wx, Wp; block 0 also zeros all 1024 flag ints
// (claim counters, barrier counter, fast flags, mirror flags).
// ---------------------------------------------------------------------------
__global__ __launch_bounds__(256) void cvt_kernel(
    const float4* __restrict__ x, const float4* __restrict__ wx,
    const float4* __restrict__ wp,
    u32* __restrict__ xb, u32* __restrict__ wxb, u32* __restrict__ wpb,
    int* __restrict__ flags)
{
    const int N1 = 9633792 / 4, N2 = 1769472 / 4;
    int i = blockIdx.x * 256 + threadIdx.x;
    if (blockIdx.x == 0) {
        flags[threadIdx.x]       = 0;
        flags[256 + threadIdx.x] = 0;
        flags[512 + threadIdx.x] = 0;
        flags[768 + threadIdx.x] = 0;
    }
    const float4* src; u32* dst; int off;
    if (i < N1)            { src = x;  dst = xb;  off = i; }
    else if (i < N1 + N2)  { src = wx; dst = wxb; off = i - N1; }
    else                   { src = wp; dst = wpb; off = i - N1 - N2; }
    float4 v = src[off];
    u32 lo = (u32)f2bf(v.x) | ((u32)f2bf(v.y) << 16);
    u32 hi = (u32)f2bf(v.z) | ((u32)f2bf(v.w) << 16);
    dst[(size_t)off * 2]     = lo;
    dst[(size_t)off * 2 + 1] = hi;
}

// ---------------------------------------------------------------------------
// GEMM: out[M][N] = A[M][K] @ B[N][K]^T   (A,B bf16 row-major K-contiguous)
// MODE 1: += bias[col], bf16 out remapped to [n][b][col] with m = b*196+n
// MODE 0: fp32 out; A rows are m = n*64+b, output row remapped to b*196+n
// ---------------------------------------------------------------------------
template<int MODE>
__global__ __launch_bounds__(256) void gemm_bt(
    const u16* __restrict__ A, const u16* __restrict__ B,
    const float* __restrict__ bias, void* __restrict__ outv)
{
    __shared__ u16 As[128 * 40];
    __shared__ u16 Bs[128 * 40];
    const int tid  = threadIdx.x;
    const int lane = tid & 63;
    const int wv   = tid >> 6;
    const int m0 = blockIdx.y * 128;
    const int n0 = blockIdx.x * 128;
    const int wm = (wv & 1) * 64;
    const int wn = (wv >> 1) * 64;

    f32x4 acc[4][4];
#pragma unroll
    for (int i = 0; i < 4; ++i)
#pragma unroll
        for (int j = 0; j < 4; ++j) acc[i][j] = (f32x4){0.f, 0.f, 0.f, 0.f};

    const int r0 = tid >> 2, q0 = tid & 3;
    const u16* gA0 = A + (size_t)(m0 + r0)      * GK + q0 * 8;
    const u16* gA1 = A + (size_t)(m0 + r0 + 64) * GK + q0 * 8;
    const u16* gB0 = B + (size_t)(n0 + r0)      * GK + q0 * 8;
    const u16* gB1 = B + (size_t)(n0 + r0 + 64) * GK + q0 * 8;
    u16* sA0 = As + r0 * 40 + q0 * 8;
    u16* sA1 = As + (r0 + 64) * 40 + q0 * 8;
    u16* sB0 = Bs + r0 * 40 + q0 * 8;
    u16* sB1 = Bs + (r0 + 64) * 40 + q0 * 8;

    const int fr = lane & 15, fq = lane >> 4;
    const u16* fA = As + (wm + fr) * 40 + fq * 8;
    const u16* fB = Bs + (wn + fr) * 40 + fq * 8;

    for (int kt = 0; kt < GK / 32; ++kt) {
        uint4 a0 = *(const uint4*)(gA0 + kt * 32);
        uint4 a1 = *(const uint4*)(gA1 + kt * 32);
        uint4 b0 = *(const uint4*)(gB0 + kt * 32);
        uint4 b1 = *(const uint4*)(gB1 + kt * 32);
        __syncthreads();
        *(uint4*)sA0 = a0; *(uint4*)sA1 = a1;
        *(uint4*)sB0 = b0; *(uint4*)sB1 = b1;
        __syncthreads();
        bf16x8 af[4], bfr[4];
#pragma unroll
        for (int mi = 0; mi < 4; ++mi) af[mi]  = *(const bf16x8*)(fA + mi * 16 * 40);
#pragma unroll
        for (int ni = 0; ni < 4; ++ni) bfr[ni] = *(const bf16x8*)(fB + ni * 16 * 40);
#pragma unroll
        for (int mi = 0; mi < 4; ++mi)
#pragma unroll
            for (int ni = 0; ni < 4; ++ni)
                acc[mi][ni] = __builtin_amdgcn_mfma_f32_16x16x32_bf16(
                    af[mi], bfr[ni], acc[mi][ni], 0, 0, 0);
    }

    if (MODE == 1) {
        u16* out = (u16*)outv;
#pragma unroll
        for (int mi = 0; mi < 4; ++mi) {
#pragma unroll
            for (int ni = 0; ni < 4; ++ni) {
                int col = n0 + wn + ni * 16 + fr;
                float bv = bias[col];
#pragma unroll
                for (int r = 0; r < 4; ++r) {
                    int m = m0 + wm + mi * 16 + fq * 4 + r;
                    int b = m / 196;
                    int nn = m - b * 196;
                    u16 hv = f2bf(acc[mi][ni][r] + bv);
                    int other = __shfl_xor((int)hv, 1, 64);
                    if (!(lane & 1)) {
                        u32 packed = (u32)hv | (((u32)(u16)other) << 16);
                        size_t eidx = ((size_t)nn * 64 + (size_t)b) * 2304 + (size_t)col;
                        *((u32*)out + (eidx >> 1)) = packed;
                    }
                }
            }
        }
    } else {
        float* out = (float*)outv;
#pragma unroll
        for (int mi = 0; mi < 4; ++mi) {
#pragma unroll
            for (int ni = 0; ni < 4; ++ni) {
                int col = n0 + wn + ni * 16 + fr;
#pragma unroll
                for (int r = 0; r < 4; ++r) {
                    int m = m0 + wm + mi * 16 + fq * 4 + r;   // m = n*64 + b
                    int b = m & 63;
                    int nn = m >> 6;
                    out[((size_t)b * 196 + nn) * 768 + col] = acc[mi][ni][r];
                }
            }
        }
    }
}

// ---------------------------------------------------------------------------
// XCD-local (L2-coherent) primitives -- no sc-bit semantics assumed.
// Poll: buffer_inv invalidates this CU's (write-through, never-dirty) L1, so
// the following PLAIN load is guaranteed served by the XCD's L2, where the
// producer's plain write-through store provably landed (vmcnt-drained).
// ---------------------------------------------------------------------------
__device__ __forceinline__ int poll_load_l2(const int* p) {
    int v;
    asm volatile("buffer_inv\n\t"
                 "global_load_dword %0, %1, off\n\t"
                 "s_waitcnt vmcnt(0)"
                 : "=v"(v) : "v"(p) : "memory");
    return v;
}
__device__ __forceinline__ void store_plain(int* p, int v) {
    asm volatile("global_store_dword %0, %1, off"
                 :: "v"(p), "v"(v) : "memory");
}

// ---------------------------------------------------------------------------
// Batch-split GRU recurrence. Group g owns batches [g*8, g*8+8); 24 WGs per
// group each own 32 h-channels (96 gate rows). Wh slice lives in registers.
// 384 threads = 6 waves: wave (np = gate 0..2, kh = K-half 0..1) computes a
// 16(batch, 8 valid) x 32(ch) x 384(K) MFMA chain; K-halves reduced in LDS;
// gate threads (tid<256: 8 batches x 32 ch) do pointwise GRU math + publish.
// LOCAL: group is physically on one XCD (claim-verified); h + flags move
// through that XCD's L2. Liveness: bounded spin, then permanent switch to
// agent-scope mirror flags (the proven-coherent protocol) -- cannot hang.
// ---------------------------------------------------------------------------
template<bool LOCAL>
__device__ void recur_run(
    int g, int s, int tid,
    const u16* __restrict__ xz, const float* __restrict__ Wh,
    const float* __restrict__ bh, u16* __restrict__ hsx, int* flags,
    float* hzs)
{
    const int lane = tid & 63;
    const int wv   = tid >> 6;          // 0..5
    const int kh   = wv & 1;            // K half (384 each)
    const int np   = wv >> 1;           // gate index 0..2
    const int fr   = lane & 15, fq = lane >> 4;
    const int c0   = s * 32;            // this WG's h-channel base
    const int B0   = g * 8;             // this group's batch base

    // ---- one-time: Wh slice -> B-frags in registers (bf16) ----
    bf16x8 bfrag[2][12];
#pragma unroll
    for (int j = 0; j < 2; ++j) {
        int row = np * 768 + c0 + j * 16 + fr;
        const float* wp = Wh + (size_t)row * 768 + kh * 384 + fq * 8;
#pragma unroll
        for (int kk = 0; kk < 12; ++kk) {
            float4 f0 = *(const float4*)(wp + kk * 32);
            float4 f1 = *(const float4*)(wp + kk * 32 + 4);
            bf16x8 b;
            b[0] = (short)f2bf(f0.x); b[1] = (short)f2bf(f0.y);
            b[2] = (short)f2bf(f0.z); b[3] = (short)f2bf(f0.w);
            b[4] = (short)f2bf(f1.x); b[5] = (short)f2bf(f1.y);
            b[6] = (short)f2bf(f1.z); b[7] = (short)f2bf(f1.w);
            bfrag[j][kk] = b;
        }
    }

    // gate-phase constants: thread t<256 -> (batch gb, channel gi)
    const int gb = tid >> 5, gi = tid & 31;
    const int gc = c0 + gi;
    float bh0 = 0.f, bh1 = 0.f, bh2 = 0.f, hold = 0.f;
    if (tid < 256) { bh0 = bh[gc]; bh1 = bh[768 + gc]; bh2 = bh[1536 + gc]; }

    // poll mapping: surject 64 lanes onto the group's 24 flags (one line)
    int fl = lane;
    if (fl >= 48) fl -= 48; else if (fl >= 24) fl -= 24;
    int* const myflag      = &flags[FLAG0 + g * 32 + s];
    int* const mymir       = &flags[MIR0  + g * 32 + s];
    const int* const pollf = &flags[FLAG0 + g * 32 + fl];
    const int* const pollm = &flags[MIR0  + g * 32 + fl];

    bool slow = !LOCAL;   // fallback protocol polls agent-scope only

    for (int n = 0; n < NSTEP; ++n) {
        // prefetch x-projection for this step (independent of h)
        float xg0 = 0.f, xg1 = 0.f, xg2 = 0.f;
        if (tid < 256) {
            size_t xoff = ((size_t)n * 64 + (B0 + gb)) * 2304 + gc;
            xg0 = bf2f(xz[xoff]);
            xg1 = bf2f(xz[xoff + 768]);
            xg2 = bf2f(xz[xoff + 1536]);
        }

        f32x4 acc0 = (f32x4){0.f, 0.f, 0.f, 0.f};
        f32x4 acc1 = (f32x4){0.f, 0.f, 0.f, 0.f};

        if (n > 0) {
            // wait until all 24 producers of THIS group published step n-1
            if (!slow) {
                int tries = 0;
                for (;;) {
                    int v = poll_load_l2(pollf);
                    if (__all(v >= n)) break;
                    if (++tries > 3000) { slow = true; break; }  // liveness rescue
                }
            }
            if (slow) {
                const int* pp = LOCAL ? pollm : pollf;
                for (;;) {
                    int v = __hip_atomic_load(pp, __ATOMIC_RELAXED,
                                              __HIP_MEMORY_SCOPE_AGENT);
                    if (__all(v >= n)) break;
                }
            }
            // A-frags: h[n-1][B0+fr][k]; rows fr>=8 zero (M=8 padded to 16)
            const u16* ap = hsx + (size_t)(n - 1) * HSTEP
                                + (size_t)(B0 + fr) * 768 + kh * 384 + fq * 8;
            const bool arow = fr < 8;
#pragma unroll
            for (int kk = 0; kk < 12; ++kk) {
                bf16x8 a = arow ? *(const bf16x8*)(ap + kk * 32)
                                : (bf16x8){0, 0, 0, 0, 0, 0, 0, 0};
                acc0 = __builtin_amdgcn_mfma_f32_16x16x32_bf16(a, bfrag[0][kk], acc0, 0, 0, 0);
                acc1 = __builtin_amdgcn_mfma_f32_16x16x32_bf16(a, bfrag[1][kk], acc1, 0, 0, 0);
            }
        }

        // partial h_zrn (per K-half) -> LDS: hzs[kh][batch][np*32 + j*16 + fr]
#pragma unroll
        for (int r = 0; r < 4; ++r) {
            int b = fq * 4 + r;
            if (b < 8) {
                hzs[(kh * 8 + b) * 96 + np * 32 + fr]      = acc0[r];
                hzs[(kh * 8 + b) * 96 + np * 32 + 16 + fr] = acc1[r];
            }
        }
        __syncthreads();

        if (tid < 256) {
            float h0 = hzs[gb * 96 + gi]      + hzs[(8 + gb) * 96 + gi]      + bh0;
            float h1 = hzs[gb * 96 + 32 + gi] + hzs[(8 + gb) * 96 + 32 + gi] + bh1;
            float h2 = hzs[gb * 96 + 64 + gi] + hzs[(8 + gb) * 96 + 64 + gi] + bh2;
            float z   = 1.f / (1.f + __expf(-(xg0 + h0)));
            float rr2 = 1.f / (1.f + __expf(-(xg1 + h1)));
            float pre = xg2 + rr2 * h2;
            float e2  = __expf(-2.f * pre);
            float nc  = (1.f - e2) / (1.f + e2);
            float hnew = (1.f - z) * nc + z * hold;
            hold = hnew;

            // pack 4 channels -> one 8B store per 4 threads
            u16 hv = f2bf(hnew);
            u32 other = ((u32)__shfl_xor((int)hv, 1, 64)) & 0xffffu;
            u32 v01 = (u32)hv | (other << 16);
            u32 v23 = (u32)__shfl_xor((int)v01, 2, 64);
            if ((tid & 3) == 0) {
                u64 q = (u64)v01 | ((u64)v23 << 32);
                size_t ofs = (size_t)n * HSTEP + (size_t)(B0 + gb) * 768 + gc;
                u64* p = (u64*)(hsx + ofs);
                if (LOCAL) {
                    *p = q;   // plain write-through -> this XCD's L2
                } else {
                    __hip_atomic_store(p, q, __ATOMIC_RELAXED, __HIP_MEMORY_SCOPE_AGENT);
                }
            }
        }
        asm volatile("s_waitcnt vmcnt(0)" ::: "memory");  // h visible before flag
        __syncthreads();
        if (LOCAL) {
            if (tid == 0)
                store_plain(myflag, n + 1);                         // fast (L2)
            else if (tid == 64)
                __hip_atomic_store(mymir, n + 1, __ATOMIC_RELAXED,
                                   __HIP_MEMORY_SCOPE_AGENT);       // rescue (L3)
        } else {
            if (tid == 0)
                __hip_atomic_store(myflag, n + 1, __ATOMIC_RELAXED,
                                   __HIP_MEMORY_SCOPE_AGENT);
        }
    }
}

// ---------------------------------------------------------------------------
// Persistent cooperative kernel: dynamic XCD claiming + dispatch.
// flags ints: [0..7] per-XCD claim counters, [15] barrier counter,
// [FLAG0 + g*32 + s] fast step flags, [MIR0 + g*32 + s] agent mirrors.
// ---------------------------------------------------------------------------
__global__ __launch_bounds__(384) void recur2_kernel(
    const u16* __restrict__ xz, const float* __restrict__ Wh,
    const float* __restrict__ bh, u16* __restrict__ hsx, int* flags)
{
    __shared__ float hzs[2 * 8 * 96];
    __shared__ int sh_g, sh_s;
    const int tid = threadIdx.x;

    // one-time: invalidate stale (previous-iteration) L1/L2 lines
    __builtin_amdgcn_fence(__ATOMIC_ACQUIRE, "agent");

    if (tid == 0) {
        u32 xcc = 0;
        asm volatile("s_getreg_b32 %0, hwreg(HW_REG_XCC_ID)" : "=s"(xcc));
        int gg = (int)(xcc & 7u);
        sh_g = gg;
        sh_s = __hip_atomic_fetch_add(&flags[gg], 1, __ATOMIC_ACQ_REL,
                                      __HIP_MEMORY_SCOPE_AGENT);
        // one-time grid barrier (cooperative launch => all NBLK co-resident)
        __hip_atomic_fetch_add(&flags[15], 1, __ATOMIC_ACQ_REL,
                               __HIP_MEMORY_SCOPE_AGENT);
        while (__hip_atomic_load(&flags[15], __ATOMIC_ACQUIRE,
                                 __HIP_MEMORY_SCOPE_AGENT) < NBLK) {}
    }
    __syncthreads();
    const int g = sh_g, s = sh_s;

    bool ok = true;
#pragma unroll
    for (int x = 0; x < 8; ++x)
        ok &= (__hip_atomic_load(&flags[x], __ATOMIC_RELAXED,
                                 __HIP_MEMORY_SCOPE_AGENT) >= PWG);

    if (ok) {
        // groups physically XCD-local by construction -> L2-scope protocol
        if (s < PWG)
            recur_run<true>(g, s, tid, xz, Wh, bh, hsx, flags, hzs);
    } else {
        // placement surprise: device-scope protocol, any layout (proven)
        const int bid = blockIdx.x;
        if (bid < 8 * PWG)
            recur_run<false>(bid & 7, bid >> 3, tid, xz, Wh, bh, hsx, flags, hzs);
    }
}

// ---------------------------------------------------------------------------
extern "C" void kernel_launch(void* const* d_in, const int* in_sizes, int n_in,
                              void* d_out, int out_size, void* d_ws, size_t ws_size,
                              hipStream_t stream)
{
    const float* x  = (const float*)d_in[0];
    const float* Wx = (const float*)d_in[1];
    const float* bx = (const float*)d_in[2];
    const float* Wh = (const float*)d_in[3];
    const float* bh = (const float*)d_in[4];
    const float* Wp = (const float*)d_in[5];
    float* out = (float*)d_out;

    char* ws = (char*)d_ws;
    size_t off = 0;
    auto wsalloc = [&](size_t bytes) -> void* {
        void* p = ws + off;
        off += (bytes + 255) & ~(size_t)255;
        return p;
    };
    u16* xb   = (u16*)wsalloc(9633792ull * 2);            // x bf16 [12544][768]
    u16* wxb  = (u16*)wsalloc(1769472ull * 2);            // Wx bf16 [2304][768]
    u16* wpb  = (u16*)wsalloc(589824ull * 2);             // Wp bf16 [768][768]
    u16* xzrn = (u16*)wsalloc(196ull * 64 * 2304 * 2);    // [n][b][3C] bf16
    u16* hsx  = (u16*)wsalloc(196ull * 64 * 768 * 2);     // [n][b][C] bf16
    int* flags = (int*)wsalloc(4096);                     // 1024 ints

    // 1) converts (+ zero claim counters / barrier / step flags / mirrors)
    cvt_kernel<<<11712, 256, 0, stream>>>(
        (const float4*)x, (const float4*)Wx, (const float4*)Wp,
        (u32*)xb, (u32*)wxb, (u32*)wpb, flags);

    // 2) x_zrn = seq @ Wx^T + bx  ->  [n][b][3C] bf16
    gemm_bt<1><<<dim3(18, 98), 256, 0, stream>>>(xb, wxb, bx, (void*)xzrn);

    // 3) cooperative batch-split recurrence (256 WGs claim XCDs dynamically)
    {
        const u16* a0 = xzrn; const float* a1 = Wh; const float* a2 = bh;
        u16* a3 = hsx; int* a4 = flags;
        void* args[5] = { &a0, &a1, &a2, &a3, &a4 };
        hipLaunchCooperativeKernel((void*)recur2_kernel, dim3(NBLK), dim3(384),
                                   args, 0, stream);
    }

    // 4) y = hsx @ Wp^T -> d_out fp32 (rows m = n*64+b, remapped on store)
    gemm_bt<0><<<dim3(6, 98), 256, 0, stream>>>(hsx, wpb, nullptr, (void*)out);
}

// Round 4
// 1381.453 us; speedup vs baseline: 1.0832x; 1.0832x over previous
//
#include <hip/hip_runtime.h>

typedef unsigned short u16;
typedef unsigned int   u32;
typedef unsigned long long u64;
typedef __attribute__((ext_vector_type(8))) short bf16x8;
typedef __attribute__((ext_vector_type(4))) float f32x4;

#define GK 768            // K dim of all GEMMs
#define NSTEP 196
#define HSTEP 49152       // 64*768 elements per step slab
#define PWG 24            // workgroups per batch-group (8 groups x 24 = 192 active)
#define NBLK 256          // launched workgroups (claim protocol)
#define FLAG0 32          // fast step-flags base (plain stores, XCD-local L2)
#define MIR0 512          // agent-scope mirror flags base (liveness rescue)

__device__ __forceinline__ u16 f2bf(float f) {
    u32 u = __float_as_uint(f);
    u = (u + 0x7fffu + ((u >> 16) & 1u)) >> 16;
    return (u16)u;
}
__device__ __forceinline__ float bf2f(u16 h) { return __uint_as_float(((u32)h) << 16); }

// ---------------------------------------------------------------------------
// fp32 -> bf16 convert for x, Wx, Wp; block 0 also zeros all 1024 flag ints
// (claim counters, barrier counter, fast flags, mirror flags).
// ---------------------------------------------------------------------------
__global__ __launch_bounds__(256) void cvt_kernel(
    const float4* __restrict__ x, const float4* __restrict__ wx,
    const float4* __restrict__ wp,
    u32* __restrict__ xb, u32* __restrict__ wxb, u32* __restrict__ wpb,
    int* __restrict__ flags)
{
    const int N1 = 9633792 / 4, N2 = 1769472 / 4;
    int i = blockIdx.x * 256 + threadIdx.x;
    if (blockIdx.x == 0) {
        flags[threadIdx.x]       = 0;
        flags[256 + threadIdx.x] = 0;
        flags[512 + threadIdx.x] = 0;
        flags[768 + threadIdx.x] = 0;
    }
    const float4* src; u32* dst; int off;
    if (i < N1)            { src = x;  dst = xb;  off = i; }
    else if (i < N1 + N2)  { src = wx; dst = wxb; off = i - N1; }
    else                   { src = wp; dst = wpb; off = i - N1 - N2; }
    float4 v = src[off];
    u32 lo = (u32)f2bf(v.x) | ((u32)f2bf(v.y) << 16);
    u32 hi = (u32)f2bf(v.z) | ((u32)f2bf(v.w) << 16);
    dst[(size_t)off * 2]     = lo;
    dst[(size_t)off * 2 + 1] = hi;
}

// ---------------------------------------------------------------------------
// GEMM: out[M][N] = A[M][K] @ B[N][K]^T   (A,B bf16 row-major K-contiguous)
// MODE 1: += bias[col], bf16 out remapped to [n][b][col] with m = b*196+n
// MODE 0: fp32 out; A rows are m = n*64+b, output row remapped to b*196+n
// ---------------------------------------------------------------------------
template<int MODE>
__global__ __launch_bounds__(256) void gemm_bt(
    const u16* __restrict__ A, const u16* __restrict__ B,
    const float* __restrict__ bias, void* __restrict__ outv)
{
    __shared__ u16 As[128 * 40];
    __shared__ u16 Bs[128 * 40];
    const int tid  = threadIdx.x;
    const int lane = tid & 63;
    const int wv   = tid >> 6;
    const int m0 = blockIdx.y * 128;
    const int n0 = blockIdx.x * 128;
    const int wm = (wv & 1) * 64;
    const int wn = (wv >> 1) * 64;

    f32x4 acc[4][4];
#pragma unroll
    for (int i = 0; i < 4; ++i)
#pragma unroll
        for (int j = 0; j < 4; ++j) acc[i][j] = (f32x4){0.f, 0.f, 0.f, 0.f};

    const int r0 = tid >> 2, q0 = tid & 3;
    const u16* gA0 = A + (size_t)(m0 + r0)      * GK + q0 * 8;
    const u16* gA1 = A + (size_t)(m0 + r0 + 64) * GK + q0 * 8;
    const u16* gB0 = B + (size_t)(n0 + r0)      * GK + q0 * 8;
    const u16* gB1 = B + (size_t)(n0 + r0 + 64) * GK + q0 * 8;
    u16* sA0 = As + r0 * 40 + q0 * 8;
    u16* sA1 = As + (r0 + 64) * 40 + q0 * 8;
    u16* sB0 = Bs + r0 * 40 + q0 * 8;
    u16* sB1 = Bs + (r0 + 64) * 40 + q0 * 8;

    const int fr = lane & 15, fq = lane >> 4;
    const u16* fA = As + (wm + fr) * 40 + fq * 8;
    const u16* fB = Bs + (wn + fr) * 40 + fq * 8;

    for (int kt = 0; kt < GK / 32; ++kt) {
        uint4 a0 = *(const uint4*)(gA0 + kt * 32);
        uint4 a1 = *(const uint4*)(gA1 + kt * 32);
        uint4 b0 = *(const uint4*)(gB0 + kt * 32);
        uint4 b1 = *(const uint4*)(gB1 + kt * 32);
        __syncthreads();
        *(uint4*)sA0 = a0; *(uint4*)sA1 = a1;
        *(uint4*)sB0 = b0; *(uint4*)sB1 = b1;
        __syncthreads();
        bf16x8 af[4], bfr[4];
#pragma unroll
        for (int mi = 0; mi < 4; ++mi) af[mi]  = *(const bf16x8*)(fA + mi * 16 * 40);
#pragma unroll
        for (int ni = 0; ni < 4; ++ni) bfr[ni] = *(const bf16x8*)(fB + ni * 16 * 40);
#pragma unroll
        for (int mi = 0; mi < 4; ++mi)
#pragma unroll
            for (int ni = 0; ni < 4; ++ni)
                acc[mi][ni] = __builtin_amdgcn_mfma_f32_16x16x32_bf16(
                    af[mi], bfr[ni], acc[mi][ni], 0, 0, 0);
    }

    if (MODE == 1) {
        u16* out = (u16*)outv;
#pragma unroll
        for (int mi = 0; mi < 4; ++mi) {
#pragma unroll
            for (int ni = 0; ni < 4; ++ni) {
                int col = n0 + wn + ni * 16 + fr;
                float bv = bias[col];
#pragma unroll
                for (int r = 0; r < 4; ++r) {
                    int m = m0 + wm + mi * 16 + fq * 4 + r;
                    int b = m / 196;
                    int nn = m - b * 196;
                    u16 hv = f2bf(acc[mi][ni][r] + bv);
                    int other = __shfl_xor((int)hv, 1, 64);
                    if (!(lane & 1)) {
                        u32 packed = (u32)hv | (((u32)(u16)other) << 16);
                        size_t eidx = ((size_t)nn * 64 + (size_t)b) * 2304 + (size_t)col;
                        *((u32*)out + (eidx >> 1)) = packed;
                    }
                }
            }
        }
    } else {
        float* out = (float*)outv;
#pragma unroll
        for (int mi = 0; mi < 4; ++mi) {
#pragma unroll
            for (int ni = 0; ni < 4; ++ni) {
                int col = n0 + wn + ni * 16 + fr;
#pragma unroll
                for (int r = 0; r < 4; ++r) {
                    int m = m0 + wm + mi * 16 + fq * 4 + r;   // m = n*64 + b
                    int b = m & 63;
                    int nn = m >> 6;
                    out[((size_t)b * 196 + nn) * 768 + col] = acc[mi][ni][r];
                }
            }
        }
    }
}

// ---------------------------------------------------------------------------
// Poll primitives.
// Fast poll: global_load sc0 -- per gfx940/950 LLVM memory-model emission,
// sc0 loads bypass the CU's L1 and are served by the XCD's L2 (~250cy).
// NO per-iteration cache maintenance (R2's per-poll buffer_inv serialized the
// CU memory pipe and cost ~5us/step). If sc0 semantics are wrong on this HW,
// the bounded spin trips and we permanently switch to the agent-scope mirror
// protocol (proven coherent) -- cannot hang, just slow.
// l1_inv: ONE whole-L1 invalidate per wave per step, after the flag confirms
// and before the h reads -- preserves R2's proven h-freshness guarantee.
// ---------------------------------------------------------------------------
__device__ __forceinline__ int poll_load_sc0(const int* p) {
    int v;
    asm volatile("global_load_dword %0, %1, off sc0\n\t"
                 "s_waitcnt vmcnt(0)"
                 : "=v"(v) : "v"(p) : "memory");
    return v;
}
__device__ __forceinline__ void l1_inv() {
    asm volatile("buffer_inv" ::: "memory");
}
__device__ __forceinline__ void store_plain(int* p, int v) {
    asm volatile("global_store_dword %0, %1, off"
                 :: "v"(p), "v"(v) : "memory");
}

// ---------------------------------------------------------------------------
// Batch-split GRU recurrence. Group g owns batches [g*8, g*8+8); 24 WGs per
// group each own 32 h-channels (96 gate rows). Wh slice lives in registers.
// 384 threads = 6 waves: wave (np = gate 0..2, kh = K-half 0..1) computes a
// 16(batch, 8 valid) x 32(ch) x 384(K) MFMA chain; K-halves reduced in LDS;
// gate threads (tid<256: 8 batches x 32 ch) do pointwise GRU math + publish.
// LOCAL: group is physically on one XCD (claim-verified); h + flags move
// through that XCD's L2.
// ---------------------------------------------------------------------------
template<bool LOCAL>
__device__ void recur_run(
    int g, int s, int tid,
    const u16* __restrict__ xz, const float* __restrict__ Wh,
    const float* __restrict__ bh, u16* __restrict__ hsx, int* flags,
    float* hzs)
{
    const int lane = tid & 63;
    const int wv   = tid >> 6;          // 0..5
    const int kh   = wv & 1;            // K half (384 each)
    const int np   = wv >> 1;           // gate index 0..2
    const int fr   = lane & 15, fq = lane >> 4;
    const int c0   = s * 32;            // this WG's h-channel base
    const int B0   = g * 8;             // this group's batch base

    // ---- one-time: Wh slice -> B-frags in registers (bf16) ----
    bf16x8 bfrag[2][12];
#pragma unroll
    for (int j = 0; j < 2; ++j) {
        int row = np * 768 + c0 + j * 16 + fr;
        const float* wp = Wh + (size_t)row * 768 + kh * 384 + fq * 8;
#pragma unroll
        for (int kk = 0; kk < 12; ++kk) {
            float4 f0 = *(const float4*)(wp + kk * 32);
            float4 f1 = *(const float4*)(wp + kk * 32 + 4);
            bf16x8 b;
            b[0] = (short)f2bf(f0.x); b[1] = (short)f2bf(f0.y);
            b[2] = (short)f2bf(f0.z); b[3] = (short)f2bf(f0.w);
            b[4] = (short)f2bf(f1.x); b[5] = (short)f2bf(f1.y);
            b[6] = (short)f2bf(f1.z); b[7] = (short)f2bf(f1.w);
            bfrag[j][kk] = b;
        }
    }

    // gate-phase constants: thread t<256 -> (batch gb, channel gi)
    const int gb = tid >> 5, gi = tid & 31;
    const int gc = c0 + gi;
    float bh0 = 0.f, bh1 = 0.f, bh2 = 0.f, hold = 0.f;
    if (tid < 256) { bh0 = bh[gc]; bh1 = bh[768 + gc]; bh2 = bh[1536 + gc]; }

    // poll mapping: surject 64 lanes onto the group's 24 flags (one line)
    int fl = lane;
    if (fl >= 48) fl -= 48; else if (fl >= 24) fl -= 24;
    int* const myflag      = &flags[FLAG0 + g * 32 + s];
    int* const mymir       = &flags[MIR0  + g * 32 + s];
    const int* const pollf = &flags[FLAG0 + g * 32 + fl];
    const int* const pollm = &flags[MIR0  + g * 32 + fl];

    bool slow = !LOCAL;   // fallback protocol polls agent-scope only

    for (int n = 0; n < NSTEP; ++n) {
        // prefetch x-projection for this step (independent of h)
        float xg0 = 0.f, xg1 = 0.f, xg2 = 0.f;
        if (tid < 256) {
            size_t xoff = ((size_t)n * 64 + (B0 + gb)) * 2304 + gc;
            xg0 = bf2f(xz[xoff]);
            xg1 = bf2f(xz[xoff + 768]);
            xg2 = bf2f(xz[xoff + 1536]);
        }

        f32x4 acc0 = (f32x4){0.f, 0.f, 0.f, 0.f};
        f32x4 acc1 = (f32x4){0.f, 0.f, 0.f, 0.f};

        if (n > 0) {
            // wait until all 24 producers of THIS group published step n-1
            if (!slow) {
                int tries = 0;
                for (;;) {
                    int v = poll_load_sc0(pollf);
                    if (__all(v >= n)) break;
                    if (++tries > 2048) { slow = true; break; }  // liveness rescue
                }
            }
            if (slow) {
                const int* pp = LOCAL ? pollm : pollf;
                for (;;) {
                    int v = __hip_atomic_load(pp, __ATOMIC_RELAXED,
                                              __HIP_MEMORY_SCOPE_AGENT);
                    if (__all(v >= n)) break;
                }
            }
            // one L1 invalidate per step: guarantee h reads are L2-fresh
            l1_inv();
            // A-frags: h[n-1][B0+fr][k]; rows fr>=8 zero (M=8 padded to 16)
            const u16* ap = hsx + (size_t)(n - 1) * HSTEP
                                + (size_t)(B0 + fr) * 768 + kh * 384 + fq * 8;
            const bool arow = fr < 8;
#pragma unroll
            for (int kk = 0; kk < 12; ++kk) {
                bf16x8 a = arow ? *(const bf16x8*)(ap + kk * 32)
                                : (bf16x8){0, 0, 0, 0, 0, 0, 0, 0};
                acc0 = __builtin_amdgcn_mfma_f32_16x16x32_bf16(a, bfrag[0][kk], acc0, 0, 0, 0);
                acc1 = __builtin_amdgcn_mfma_f32_16x16x32_bf16(a, bfrag[1][kk], acc1, 0, 0, 0);
            }
        }

        // partial h_zrn (per K-half) -> LDS: hzs[kh][batch][np*32 + j*16 + fr]
#pragma unroll
        for (int r = 0; r < 4; ++r) {
            int b = fq * 4 + r;
            if (b < 8) {
                hzs[(kh * 8 + b) * 96 + np * 32 + fr]      = acc0[r];
                hzs[(kh * 8 + b) * 96 + np * 32 + 16 + fr] = acc1[r];
            }
        }
        __syncthreads();

        if (tid < 256) {
            float h0 = hzs[gb * 96 + gi]      + hzs[(8 + gb) * 96 + gi]      + bh0;
            float h1 = hzs[gb * 96 + 32 + gi] + hzs[(8 + gb) * 96 + 32 + gi] + bh1;
            float h2 = hzs[gb * 96 + 64 + gi] + hzs[(8 + gb) * 96 + 64 + gi] + bh2;
            float z   = 1.f / (1.f + __expf(-(xg0 + h0)));
            float rr2 = 1.f / (1.f + __expf(-(xg1 + h1)));
            float pre = xg2 + rr2 * h2;
            float e2  = __expf(-2.f * pre);
            float nc  = (1.f - e2) / (1.f + e2);
            float hnew = (1.f - z) * nc + z * hold;
            hold = hnew;

            // pack 4 channels -> one 8B store per 4 threads
            u16 hv = f2bf(hnew);
            u32 other = ((u32)__shfl_xor((int)hv, 1, 64)) & 0xffffu;
            u32 v01 = (u32)hv | (other << 16);
            u32 v23 = (u32)__shfl_xor((int)v01, 2, 64);
            if ((tid & 3) == 0) {
                u64 q = (u64)v01 | ((u64)v23 << 32);
                size_t ofs = (size_t)n * HSTEP + (size_t)(B0 + gb) * 768 + gc;
                u64* p = (u64*)(hsx + ofs);
                if (LOCAL) {
                    *p = q;   // plain write-through -> this XCD's L2
                } else {
                    __hip_atomic_store(p, q, __ATOMIC_RELAXED, __HIP_MEMORY_SCOPE_AGENT);
                }
            }
        }
        asm volatile("s_waitcnt vmcnt(0)" ::: "memory");  // h visible before flag
        __syncthreads();
        if (LOCAL) {
            if (tid == 0)
                store_plain(myflag, n + 1);                         // fast (L2)
            else if (tid == 64)
                __hip_atomic_store(mymir, n + 1, __ATOMIC_RELAXED,
                                   __HIP_MEMORY_SCOPE_AGENT);       // rescue (L3)
        } else {
            if (tid == 0)
                __hip_atomic_store(myflag, n + 1, __ATOMIC_RELAXED,
                                   __HIP_MEMORY_SCOPE_AGENT);
        }
    }
}

// ---------------------------------------------------------------------------
// Persistent cooperative kernel: dynamic XCD claiming + dispatch.
// flags ints: [0..7] per-XCD claim counters, [15] barrier counter,
// [FLAG0 + g*32 + s] fast step flags, [MIR0 + g*32 + s] agent mirrors.
// ---------------------------------------------------------------------------
__global__ __launch_bounds__(384) void recur2_kernel(
    const u16* __restrict__ xz, const float* __restrict__ Wh,
    const float* __restrict__ bh, u16* __restrict__ hsx, int* flags)
{
    __shared__ float hzs[2 * 8 * 96];
    __shared__ int sh_g, sh_s;
    const int tid = threadIdx.x;

    // one-time: invalidate stale (previous-iteration) L1/L2 lines
    __builtin_amdgcn_fence(__ATOMIC_ACQUIRE, "agent");

    if (tid == 0) {
        u32 xcc = 0;
        asm volatile("s_getreg_b32 %0, hwreg(HW_REG_XCC_ID)" : "=s"(xcc));
        int gg = (int)(xcc & 7u);
        sh_g = gg;
        sh_s = __hip_atomic_fetch_add(&flags[gg], 1, __ATOMIC_ACQ_REL,
                                      __HIP_MEMORY_SCOPE_AGENT);
        // one-time grid barrier (cooperative launch => all NBLK co-resident)
        __hip_atomic_fetch_add(&flags[15], 1, __ATOMIC_ACQ_REL,
                               __HIP_MEMORY_SCOPE_AGENT);
        while (__hip_atomic_load(&flags[15], __ATOMIC_ACQUIRE,
                                 __HIP_MEMORY_SCOPE_AGENT) < NBLK) {}
    }
    __syncthreads();
    const int g = sh_g, s = sh_s;

    bool ok = true;
#pragma unroll
    for (int x = 0; x < 8; ++x)
        ok &= (__hip_atomic_load(&flags[x], __ATOMIC_RELAXED,
                                 __HIP_MEMORY_SCOPE_AGENT) >= PWG);

    if (ok) {
        // groups physically XCD-local by construction -> L2-scope protocol
        if (s < PWG)
            recur_run<true>(g, s, tid, xz, Wh, bh, hsx, flags, hzs);
    } else {
        // placement surprise: device-scope protocol, any layout (proven)
        const int bid = blockIdx.x;
        if (bid < 8 * PWG)
            recur_run<false>(bid & 7, bid >> 3, tid, xz, Wh, bh, hsx, flags, hzs);
    }
}

// ---------------------------------------------------------------------------
extern "C" void kernel_launch(void* const* d_in, const int* in_sizes, int n_in,
                              void* d_out, int out_size, void* d_ws, size_t ws_size,
                              hipStream_t stream)
{
    const float* x  = (const float*)d_in[0];
    const float* Wx = (const float*)d_in[1];
    const float* bx = (const float*)d_in[2];
    const float* Wh = (const float*)d_in[3];
    const float* bh = (const float*)d_in[4];
    const float* Wp = (const float*)d_in[5];
    float* out = (float*)d_out;

    char* ws = (char*)d_ws;
    size_t off = 0;
    auto wsalloc = [&](size_t bytes) -> void* {
        void* p = ws + off;
        off += (bytes + 255) & ~(size_t)255;
        return p;
    };
    u16* xb   = (u16*)wsalloc(9633792ull * 2);            // x bf16 [12544][768]
    u16* wxb  = (u16*)wsalloc(1769472ull * 2);            // Wx bf16 [2304][768]
    u16* wpb  = (u16*)wsalloc(589824ull * 2);             // Wp bf16 [768][768]
    u16* xzrn = (u16*)wsalloc(196ull * 64 * 2304 * 2);    // [n][b][3C] bf16
    u16* hsx  = (u16*)wsalloc(196ull * 64 * 768 * 2);     // [n][b][C] bf16
    int* flags = (int*)wsalloc(4096);                     // 1024 ints

    // 1) converts (+ zero claim counters / barrier / step flags / mirrors)
    cvt_kernel<<<11712, 256, 0, stream>>>(
        (const float4*)x, (const float4*)Wx, (const float4*)Wp,
        (u32*)xb, (u32*)wxb, (u32*)wpb, flags);

    // 2) x_zrn = seq @ Wx^T + bx  ->  [n][b][3C] bf16
    gemm_bt<1><<<dim3(18, 98), 256, 0, stream>>>(xb, wxb, bx, (void*)xzrn);

    // 3) cooperative batch-split recurrence (256 WGs claim XCDs dynamically)
    {
        const u16* a0 = xzrn; const float* a1 = Wh; const float* a2 = bh;
        u16* a3 = hsx; int* a4 = flags;
        void* args[5] = { &a0, &a1, &a2, &a3, &a4 };
        hipLaunchCooperativeKernel((void*)recur2_kernel, dim3(NBLK), dim3(384),
                                   args, 0, stream);
    }

    // 4) y = hsx @ Wp^T -> d_out fp32 (rows m = n*64+b, remapped on store)
    gemm_bt<0><<<dim3(6, 98), 256, 0, stream>>>(hsx, wpb, nullptr, (void*)out);
}

// Round 5
// 1172.232 us; speedup vs baseline: 1.2766x; 1.1785x over previous
//
#include <hip/hip_runtime.h>

typedef unsigned short u16;
typedef unsigned int   u32;
typedef unsigned long long u64;
typedef __attribute__((ext_vector_type(8))) short bf16x8;
typedef __attribute__((ext_vector_type(4))) float f32x4;

#define GK 768            // K dim of all GEMMs
#define NSTEP 196
#define HSTEP 49152       // 64*768 elements per step slab
#define PWG 24            // workgroups per batch-group (8 groups x 24 active)
#define NBLK 256          // launched workgroups (claim protocol)
#define FLAG0 32          // fast step-flags base (sc0 stores, XCD-local L2)
#define MIR0 512          // agent-scope mirror flags base (liveness rescue)

__device__ __forceinline__ u16 f2bf(float f) {
    u32 u = __float_as_uint(f);
    u = (u + 0x7fffu + ((u >> 16) & 1u)) >> 16;
    return (u16)u;
}
__device__ __forceinline__ float bf2f(u16 h) { return __uint_as_float(((u32)h) << 16); }

// ---------------------------------------------------------------------------
// fp32 -> bf16 convert for x, Wx, Wp; block 0 also zeros all 1024 flag ints
// (claim counters, barrier counter, fast flags, mirror flags).
// ---------------------------------------------------------------------------
__global__ __launch_bounds__(256) void cvt_kernel(
    const float4* __restrict__ x, const float4* __restrict__ wx,
    const float4* __restrict__ wp,
    u32* __restrict__ xb, u32* __restrict__ wxb, u32* __restrict__ wpb,
    int* __restrict__ flags)
{
    const int N1 = 9633792 / 4, N2 = 1769472 / 4;
    int i = blockIdx.x * 256 + threadIdx.x;
    if (blockIdx.x == 0) {
        flags[threadIdx.x]       = 0;
        flags[256 + threadIdx.x] = 0;
        flags[512 + threadIdx.x] = 0;
        flags[768 + threadIdx.x] = 0;
    }
    const float4* src; u32* dst; int off;
    if (i < N1)            { src = x;  dst = xb;  off = i; }
    else if (i < N1 + N2)  { src = wx; dst = wxb; off = i - N1; }
    else                   { src = wp; dst = wpb; off = i - N1 - N2; }
    float4 v = src[off];
    u32 lo = (u32)f2bf(v.x) | ((u32)f2bf(v.y) << 16);
    u32 hi = (u32)f2bf(v.z) | ((u32)f2bf(v.w) << 16);
    dst[(size_t)off * 2]     = lo;
    dst[(size_t)off * 2 + 1] = hi;
}

// ---------------------------------------------------------------------------
// GEMM: out[M][N] = A[M][K] @ B[N][K]^T   (A,B bf16 row-major K-contiguous)
// MODE 1: += bias[col], bf16 out remapped to [n][b][col] with m = b*196+n
// MODE 0: fp32 out; A rows are m = n*64+b, output row remapped to b*196+n
// ---------------------------------------------------------------------------
template<int MODE>
__global__ __launch_bounds__(256) void gemm_bt(
    const u16* __restrict__ A, const u16* __restrict__ B,
    const float* __restrict__ bias, void* __restrict__ outv)
{
    __shared__ u16 As[128 * 40];
    __shared__ u16 Bs[128 * 40];
    const int tid  = threadIdx.x;
    const int lane = tid & 63;
    const int wv   = tid >> 6;
    const int m0 = blockIdx.y * 128;
    const int n0 = blockIdx.x * 128;
    const int wm = (wv & 1) * 64;
    const int wn = (wv >> 1) * 64;

    f32x4 acc[4][4];
#pragma unroll
    for (int i = 0; i < 4; ++i)
#pragma unroll
        for (int j = 0; j < 4; ++j) acc[i][j] = (f32x4){0.f, 0.f, 0.f, 0.f};

    const int r0 = tid >> 2, q0 = tid & 3;
    const u16* gA0 = A + (size_t)(m0 + r0)      * GK + q0 * 8;
    const u16* gA1 = A + (size_t)(m0 + r0 + 64) * GK + q0 * 8;
    const u16* gB0 = B + (size_t)(n0 + r0)      * GK + q0 * 8;
    const u16* gB1 = B + (size_t)(n0 + r0 + 64) * GK + q0 * 8;
    u16* sA0 = As + r0 * 40 + q0 * 8;
    u16* sA1 = As + (r0 + 64) * 40 + q0 * 8;
    u16* sB0 = Bs + r0 * 40 + q0 * 8;
    u16* sB1 = Bs + (r0 + 64) * 40 + q0 * 8;

    const int fr = lane & 15, fq = lane >> 4;
    const u16* fA = As + (wm + fr) * 40 + fq * 8;
    const u16* fB = Bs + (wn + fr) * 40 + fq * 8;

    for (int kt = 0; kt < GK / 32; ++kt) {
        uint4 a0 = *(const uint4*)(gA0 + kt * 32);
        uint4 a1 = *(const uint4*)(gA1 + kt * 32);
        uint4 b0 = *(const uint4*)(gB0 + kt * 32);
        uint4 b1 = *(const uint4*)(gB1 + kt * 32);
        __syncthreads();
        *(uint4*)sA0 = a0; *(uint4*)sA1 = a1;
        *(uint4*)sB0 = b0; *(uint4*)sB1 = b1;
        __syncthreads();
        bf16x8 af[4], bfr[4];
#pragma unroll
        for (int mi = 0; mi < 4; ++mi) af[mi]  = *(const bf16x8*)(fA + mi * 16 * 40);
#pragma unroll
        for (int ni = 0; ni < 4; ++ni) bfr[ni] = *(const bf16x8*)(fB + ni * 16 * 40);
#pragma unroll
        for (int mi = 0; mi < 4; ++mi)
#pragma unroll
            for (int ni = 0; ni < 4; ++ni)
                acc[mi][ni] = __builtin_amdgcn_mfma_f32_16x16x32_bf16(
                    af[mi], bfr[ni], acc[mi][ni], 0, 0, 0);
    }

    if (MODE == 1) {
        u16* out = (u16*)outv;
#pragma unroll
        for (int mi = 0; mi < 4; ++mi) {
#pragma unroll
            for (int ni = 0; ni < 4; ++ni) {
                int col = n0 + wn + ni * 16 + fr;
                float bv = bias[col];
#pragma unroll
                for (int r = 0; r < 4; ++r) {
                    int m = m0 + wm + mi * 16 + fq * 4 + r;
                    int b = m / 196;
                    int nn = m - b * 196;
                    u16 hv = f2bf(acc[mi][ni][r] + bv);
                    int other = __shfl_xor((int)hv, 1, 64);
                    if (!(lane & 1)) {
                        u32 packed = (u32)hv | (((u32)(u16)other) << 16);
                        size_t eidx = ((size_t)nn * 64 + (size_t)b) * 2304 + (size_t)col;
                        *((u32*)out + (eidx >> 1)) = packed;
                    }
                }
            }
        }
    } else {
        float* out = (float*)outv;
#pragma unroll
        for (int mi = 0; mi < 4; ++mi) {
#pragma unroll
            for (int ni = 0; ni < 4; ++ni) {
                int col = n0 + wn + ni * 16 + fr;
#pragma unroll
                for (int r = 0; r < 4; ++r) {
                    int m = m0 + wm + mi * 16 + fq * 4 + r;   // m = n*64 + b
                    int b = m & 63;
                    int nn = m >> 6;
                    out[((size_t)b * 196 + nn) * 768 + col] = acc[mi][ni][r];
                }
            }
        }
    }
}

// ---------------------------------------------------------------------------
// Poll primitives. sc0 (+nt: no L1 allocate) load -> L2-served within the
// XCD. sc0 store -> immediate agent-visible write-through to L2. No cache-
// maintenance ops anywhere in the loop (R2 lesson: buffer_inv serializes the
// CU memory pipe). h freshness needs NO invalidates: every hsx address is
// written once and read once, always after flag-confirm, so no stale L1 line
// can exist. Liveness: bounded fast spin, then permanent switch to the
// agent-scope mirror protocol (proven coherent) -- cannot hang.
// ---------------------------------------------------------------------------
__device__ __forceinline__ int poll_load_sc0(const int* p) {
    int v;
    asm volatile("global_load_dword %0, %1, off sc0 nt\n\t"
                 "s_waitcnt vmcnt(0)"
                 : "=v"(v) : "v"(p) : "memory");
    return v;
}
__device__ __forceinline__ void store_sc0(int* p, int v) {
    asm volatile("global_store_dword %0, %1, off sc0"
                 :: "v"(p), "v"(v) : "memory");
}

// ---------------------------------------------------------------------------
// Batch-split GRU recurrence. Group g owns batches [g*8, g*8+8); 24 WGs per
// group each own 32 h-channels (96 gate rows). Wh slice lives in registers.
// 384 threads = 6 waves: wave (np = gate 0..2, kh = K-half 0..1) computes a
// 16(batch, 8 valid) x 32(ch) x 384(K) MFMA chain; K-halves reduced in LDS;
// gate threads (tid<256: 8 batches x 32 ch) do pointwise GRU math + publish.
// xz for step n+1 is prefetched during step n's compute so the poll's
// vmcnt(0) never waits on an HBM load.
// ---------------------------------------------------------------------------
template<bool LOCAL>
__device__ void recur_run(
    int g, int s, int tid,
    const u16* __restrict__ xz, const float* __restrict__ Wh,
    const float* __restrict__ bh, u16* __restrict__ hsx, int* flags,
    float* hzs)
{
    const int lane = tid & 63;
    const int wv   = tid >> 6;          // 0..5
    const int kh   = wv & 1;            // K half (384 each)
    const int np   = wv >> 1;           // gate index 0..2
    const int fr   = lane & 15, fq = lane >> 4;
    const int c0   = s * 32;            // this WG's h-channel base
    const int B0   = g * 8;             // this group's batch base

    // ---- one-time: Wh slice -> B-frags in registers (bf16) ----
    bf16x8 bfrag[2][12];
#pragma unroll
    for (int j = 0; j < 2; ++j) {
        int row = np * 768 + c0 + j * 16 + fr;
        const float* wp = Wh + (size_t)row * 768 + kh * 384 + fq * 8;
#pragma unroll
        for (int kk = 0; kk < 12; ++kk) {
            float4 f0 = *(const float4*)(wp + kk * 32);
            float4 f1 = *(const float4*)(wp + kk * 32 + 4);
            bf16x8 b;
            b[0] = (short)f2bf(f0.x); b[1] = (short)f2bf(f0.y);
            b[2] = (short)f2bf(f0.z); b[3] = (short)f2bf(f0.w);
            b[4] = (short)f2bf(f1.x); b[5] = (short)f2bf(f1.y);
            b[6] = (short)f2bf(f1.z); b[7] = (short)f2bf(f1.w);
            bfrag[j][kk] = b;
        }
    }

    // gate-phase constants: thread t<256 -> (batch gb, channel gi)
    const int gb = tid >> 5, gi = tid & 31;
    const int gc = c0 + gi;
    float bh0 = 0.f, bh1 = 0.f, bh2 = 0.f, hold = 0.f;
    if (tid < 256) { bh0 = bh[gc]; bh1 = bh[768 + gc]; bh2 = bh[1536 + gc]; }

    // poll mapping: surject 64 lanes onto the group's 24 flags (one line)
    int fl = lane;
    if (fl >= 48) fl -= 48; else if (fl >= 24) fl -= 24;
    int* const myflag      = &flags[FLAG0 + g * 32 + s];
    int* const mymir       = &flags[MIR0  + g * 32 + s];
    const int* const pollf = &flags[FLAG0 + g * 32 + fl];
    const int* const pollm = &flags[MIR0  + g * 32 + fl];

    // preload xz for step 0
    float xgn0 = 0.f, xgn1 = 0.f, xgn2 = 0.f;
    if (tid < 256) {
        size_t xoff = (size_t)(B0 + gb) * 2304 + gc;
        xgn0 = bf2f(xz[xoff]);
        xgn1 = bf2f(xz[xoff + 768]);
        xgn2 = bf2f(xz[xoff + 1536]);
    }

    bool slow = !LOCAL;   // fallback protocol polls agent-scope only

    for (int n = 0; n < NSTEP; ++n) {
        const float xg0 = xgn0, xg1 = xgn1, xg2 = xgn2;   // prefetched

        f32x4 acc0 = (f32x4){0.f, 0.f, 0.f, 0.f};
        f32x4 acc1 = (f32x4){0.f, 0.f, 0.f, 0.f};

        if (n > 0) {
            // wait until all 24 producers of THIS group published step n-1
            if (!slow) {
                int tries = 0;
                for (;;) {
                    int v = poll_load_sc0(pollf);
                    if (__all(v >= n)) break;
                    if (++tries > 2048) { slow = true; break; }  // liveness rescue
                }
            }
            if (slow) {
                const int* pp = LOCAL ? pollm : pollf;
                for (;;) {
                    int v = __hip_atomic_load(pp, __ATOMIC_RELAXED,
                                              __HIP_MEMORY_SCOPE_AGENT);
                    if (__all(v >= n)) break;
                }
            }
            // A-frags: h[n-1][B0+fr][k]; rows fr>=8 zero (M=8 padded to 16)
            const u16* ap = hsx + (size_t)(n - 1) * HSTEP
                                + (size_t)(B0 + fr) * 768 + kh * 384 + fq * 8;
            const bool arow = fr < 8;
#pragma unroll
            for (int kk = 0; kk < 12; ++kk) {
                bf16x8 a = arow ? *(const bf16x8*)(ap + kk * 32)
                                : (bf16x8){0, 0, 0, 0, 0, 0, 0, 0};
                acc0 = __builtin_amdgcn_mfma_f32_16x16x32_bf16(a, bfrag[0][kk], acc0, 0, 0, 0);
                acc1 = __builtin_amdgcn_mfma_f32_16x16x32_bf16(a, bfrag[1][kk], acc1, 0, 0, 0);
            }
        }

        // prefetch next step's xz (latency hides under LDS/sync/gates)
        if (tid < 256) {
            int np1 = (n + 1 < NSTEP) ? n + 1 : NSTEP - 1;
            size_t xoff = ((size_t)np1 * 64 + (B0 + gb)) * 2304 + gc;
            xgn0 = bf2f(xz[xoff]);
            xgn1 = bf2f(xz[xoff + 768]);
            xgn2 = bf2f(xz[xoff + 1536]);
        }

        // partial h_zrn (per K-half) -> LDS: hzs[kh][batch][np*32 + j*16 + fr]
#pragma unroll
        for (int r = 0; r < 4; ++r) {
            int b = fq * 4 + r;
            if (b < 8) {
                hzs[(kh * 8 + b) * 96 + np * 32 + fr]      = acc0[r];
                hzs[(kh * 8 + b) * 96 + np * 32 + 16 + fr] = acc1[r];
            }
        }
        __syncthreads();

        if (tid < 256) {
            float h0 = hzs[gb * 96 + gi]      + hzs[(8 + gb) * 96 + gi]      + bh0;
            float h1 = hzs[gb * 96 + 32 + gi] + hzs[(8 + gb) * 96 + 32 + gi] + bh1;
            float h2 = hzs[gb * 96 + 64 + gi] + hzs[(8 + gb) * 96 + 64 + gi] + bh2;
            float z   = 1.f / (1.f + __expf(-(xg0 + h0)));
            float rr2 = 1.f / (1.f + __expf(-(xg1 + h1)));
            float pre = xg2 + rr2 * h2;
            float e2  = __expf(-2.f * pre);
            float nc  = (1.f - e2) / (1.f + e2);
            float hnew = (1.f - z) * nc + z * hold;
            hold = hnew;

            // pack 4 channels -> one 8B store per 4 threads
            u16 hv = f2bf(hnew);
            u32 other = ((u32)__shfl_xor((int)hv, 1, 64)) & 0xffffu;
            u32 v01 = (u32)hv | (other << 16);
            u32 v23 = (u32)__shfl_xor((int)v01, 2, 64);
            if ((tid & 3) == 0) {
                u64 q = (u64)v01 | ((u64)v23 << 32);
                size_t ofs = (size_t)n * HSTEP + (size_t)(B0 + gb) * 768 + gc;
                u64* p = (u64*)(hsx + ofs);
                if (LOCAL) {
                    *p = q;   // plain write-through -> this XCD's L2
                } else {
                    __hip_atomic_store(p, q, __ATOMIC_RELAXED, __HIP_MEMORY_SCOPE_AGENT);
                }
            }
        }
        asm volatile("s_waitcnt vmcnt(0)" ::: "memory");  // h visible before flag
        __syncthreads();
        if (LOCAL) {
            if (tid == 0)
                store_sc0(myflag, n + 1);                           // fast (L2)
            else if (tid == 320)
                __hip_atomic_store(mymir, n + 1, __ATOMIC_RELAXED,
                                   __HIP_MEMORY_SCOPE_AGENT);       // rescue (L3)
        } else {
            if (tid == 0)
                __hip_atomic_store(myflag, n + 1, __ATOMIC_RELAXED,
                                   __HIP_MEMORY_SCOPE_AGENT);
        }
    }
}

// ---------------------------------------------------------------------------
// Persistent cooperative kernel. Placement-adaptive group formation:
// each WG claims a slot on its PHYSICAL XCD; after a grid barrier, every WG
// derives from the final per-XCD counts how many whole 24-WG groups each XCD
// can host (floor(cnt/24)), prefix-sums them into global group ids, and
// activates groups 0..7. Works for balanced (32/XCD) and packed (e.g. 64x4)
// placements alike -- every group is single-XCD by construction. Only if
// fewer than 8 whole groups exist anywhere (G<8) do we fall back to the
// device-scope protocol.
// flags ints: [0..7] per-XCD claim counters, [15] barrier counter,
// [FLAG0 + g*32 + s] fast step flags, [MIR0 + g*32 + s] agent mirrors.
// ---------------------------------------------------------------------------
__global__ __launch_bounds__(384) void recur2_kernel(
    const u16* __restrict__ xz, const float* __restrict__ Wh,
    const float* __restrict__ bh, u16* __restrict__ hsx, int* flags)
{
    __shared__ float hzs[2 * 8 * 96];
    __shared__ int sh_mode, sh_g, sh_s;
    const int tid = threadIdx.x;

    // one-time: invalidate stale (previous-dispatch) L1 lines
    __builtin_amdgcn_fence(__ATOMIC_ACQUIRE, "agent");

    if (tid == 0) {
        u32 xcc = 0;
        asm volatile("s_getreg_b32 %0, hwreg(HW_REG_XCC_ID)" : "=s"(xcc));
        const int my_xcd = (int)(xcc & 7u);
        const int slot = __hip_atomic_fetch_add(&flags[my_xcd], 1, __ATOMIC_ACQ_REL,
                                                __HIP_MEMORY_SCOPE_AGENT);
        // grid barrier (cooperative launch => all NBLK co-resident)
        __hip_atomic_fetch_add(&flags[15], 1, __ATOMIC_ACQ_REL,
                               __HIP_MEMORY_SCOPE_AGENT);
        while (__hip_atomic_load(&flags[15], __ATOMIC_ACQUIRE,
                                 __HIP_MEMORY_SCOPE_AGENT) < NBLK) {}
        // derive group assignment from the measured placement
        int G = 0, pre = 0, myg = 0;
        for (int x = 0; x < 8; ++x) {
            int c  = __hip_atomic_load(&flags[x], __ATOMIC_RELAXED,
                                       __HIP_MEMORY_SCOPE_AGENT);
            int gx = c / PWG;
            if (x < my_xcd) pre += gx;
            if (x == my_xcd) myg = gx;
            G += gx;
        }
        const int grp = pre + slot / PWG;
        const bool act = (slot < myg * PWG) && (grp < 8);
        sh_mode = (G >= 8) ? (act ? 1 : 2) : 0;
        sh_g = grp;
        sh_s = slot % PWG;
    }
    __syncthreads();
    const int mode = sh_mode;

    if (mode == 1) {
        // group physically on ONE XCD by construction -> L2-scope protocol
        recur_run<true>(sh_g, sh_s, tid, xz, Wh, bh, hsx, flags, hzs);
    } else if (mode == 0) {
        // pathological placement: device-scope protocol, any layout (proven)
        const int bid = blockIdx.x;
        if (bid < 8 * PWG)
            recur_run<false>(bid & 7, bid >> 3, tid, xz, Wh, bh, hsx, flags, hzs);
    }
    // mode == 2: surplus WG, idle
}

// ---------------------------------------------------------------------------
extern "C" void kernel_launch(void* const* d_in, const int* in_sizes, int n_in,
                              void* d_out, int out_size, void* d_ws, size_t ws_size,
                              hipStream_t stream)
{
    const float* x  = (const float*)d_in[0];
    const float* Wx = (const float*)d_in[1];
    const float* bx = (const float*)d_in[2];
    const float* Wh = (const float*)d_in[3];
    const float* bh = (const float*)d_in[4];
    const float* Wp = (const float*)d_in[5];
    float* out = (float*)d_out;

    char* ws = (char*)d_ws;
    size_t off = 0;
    auto wsalloc = [&](size_t bytes) -> void* {
        void* p = ws + off;
        off += (bytes + 255) & ~(size_t)255;
        return p;
    };
    u16* xb   = (u16*)wsalloc(9633792ull * 2);            // x bf16 [12544][768]
    u16* wxb  = (u16*)wsalloc(1769472ull * 2);            // Wx bf16 [2304][768]
    u16* wpb  = (u16*)wsalloc(589824ull * 2);             // Wp bf16 [768][768]
    u16* xzrn = (u16*)wsalloc(196ull * 64 * 2304 * 2);    // [n][b][3C] bf16
    u16* hsx  = (u16*)wsalloc(196ull * 64 * 768 * 2);     // [n][b][C] bf16
    int* flags = (int*)wsalloc(4096);                     // 1024 ints

    // 1) converts (+ zero claim counters / barrier / step flags / mirrors)
    cvt_kernel<<<11712, 256, 0, stream>>>(
        (const float4*)x, (const float4*)Wx, (const float4*)Wp,
        (u32*)xb, (u32*)wxb, (u32*)wpb, flags);

    // 2) x_zrn = seq @ Wx^T + bx  ->  [n][b][3C] bf16
    gemm_bt<1><<<dim3(18, 98), 256, 0, stream>>>(xb, wxb, bx, (void*)xzrn);

    // 3) cooperative batch-split recurrence (256 WGs, placement-adaptive)
    {
        const u16* a0 = xzrn; const float* a1 = Wh; const float* a2 = bh;
        u16* a3 = hsx; int* a4 = flags;
        void* args[5] = { &a0, &a1, &a2, &a3, &a4 };
        hipLaunchCooperativeKernel((void*)recur2_kernel, dim3(NBLK), dim3(384),
                                   args, 0, stream);
    }

    // 4) y = hsx @ Wp^T -> d_out fp32 (rows m = n*64+b, remapped on store)
    gemm_bt<0><<<dim3(6, 98), 256, 0, stream>>>(hsx, wpb, nullptr, (void*)out);
}